// Round 1
// baseline (325.130 us; speedup 1.0000x reference)
//
#include <hip/hip_runtime.h>
#include <hip/hip_bf16.h>
#include <math.h>

// Problem constants (from reference)
#define NN   31      // tree nodes
#define VV   50000   // vocab
#define EE   128     // embed = enc = H = 128
#define HH   128
#define BB   64
#define LL   128
#define NLBL 104

// ---------------------------------------------------------------------------
// Generic fp32 GEMM: C[M,N] = A[M,128] * B[N,128]^T (+ bias[N])
// Tile 64x128, 256 threads, K split in 2 halves of 64 so LDS stays < 64KB.
// Thread t: rows r0..r0+3 (r0=(t/16)*4), cols (t%16)+16j, j=0..7.
// Padded f4 stride 17 -> B reads 2-way bank alias (free), A reads broadcast.
// ---------------------------------------------------------------------------
template <bool BIAS>
__global__ __launch_bounds__(256, 2) void gemm128(const float* __restrict__ A,
                                                  const float* __restrict__ Bm,
                                                  const float* __restrict__ bias,
                                                  float* __restrict__ C,
                                                  int M, int N) {
    __shared__ float4 As[64 * 17];
    __shared__ float4 Bs[128 * 17];
    const int tid = threadIdx.x;
    const int m0 = blockIdx.x * 64;
    const int n0 = blockIdx.y * 128;
    const float4* Af4 = (const float4*)A;
    const float4* Bf4 = (const float4*)Bm;

    const int r0 = (tid >> 4) * 4;
    const int cb = tid & 15;
    float acc[4][8] = {};

    for (int kk = 0; kk < 2; ++kk) {
        // stage B half-tile: 128 rows x 16 f4
        for (int f = tid; f < 128 * 16; f += 256) {
            int r = f >> 4, e = f & 15;
            Bs[r * 17 + e] = Bf4[(size_t)(n0 + r) * 32 + kk * 16 + e];
        }
        // stage A half-tile: 64 rows x 16 f4 (zero-fill OOB rows)
        for (int f = tid; f < 64 * 16; f += 256) {
            int r = f >> 4, e = f & 15;
            float4 v = make_float4(0.f, 0.f, 0.f, 0.f);
            if (m0 + r < M) v = Af4[(size_t)(m0 + r) * 32 + kk * 16 + e];
            As[r * 17 + e] = v;
        }
        __syncthreads();
        #pragma unroll
        for (int e = 0; e < 16; ++e) {
            float4 a[4], b[8];
            #pragma unroll
            for (int i = 0; i < 4; ++i) a[i] = As[(r0 + i) * 17 + e];
            #pragma unroll
            for (int j = 0; j < 8; ++j) b[j] = Bs[(cb + j * 16) * 17 + e];
            #pragma unroll
            for (int i = 0; i < 4; ++i) {
                #pragma unroll
                for (int j = 0; j < 8; ++j) {
                    acc[i][j] += a[i].x * b[j].x;
                    acc[i][j] += a[i].y * b[j].y;
                    acc[i][j] += a[i].z * b[j].z;
                    acc[i][j] += a[i].w * b[j].w;
                }
            }
        }
        __syncthreads();
    }

    #pragma unroll
    for (int i = 0; i < 4; ++i) {
        int row = m0 + r0 + i;
        if (row < M) {
            #pragma unroll
            for (int j = 0; j < 8; ++j) {
                int col = n0 + cb + j * 16;
                float v = acc[i][j];
                if (BIAS) v += bias[col];
                C[(size_t)row * N + col] = v;
            }
        }
    }
}

// ---------------------------------------------------------------------------
// Tree encode: per (b,l) position gather 31 projected-embedding rows,
// heap-accumulate subtree sums in registers, add |subtree|*Wc_b, max over
// nodes. 2 positions per 256-thread block; thread = channel (coalesced).
// ---------------------------------------------------------------------------
__global__ __launch_bounds__(256) void tree_encode(const int* __restrict__ tok,
                                                   const float* __restrict__ Wemb,
                                                   const float* __restrict__ Wcb,
                                                   float* __restrict__ enc) {
    __shared__ int st[2][NN];
    const int tid = threadIdx.x;
    const int p = tid >> 7;    // which of the 2 positions
    const int c = tid & 127;   // channel
    const int bl = blockIdx.x * 2;
    if (tid < 2 * NN) {
        int pp = tid / NN, jj = tid - pp * NN;
        st[pp][jj] = tok[(size_t)(bl + pp) * NN + jj];
    }
    __syncthreads();

    float v[NN];
    #pragma unroll
    for (int j = 0; j < NN; ++j)
        v[j] = Wemb[(size_t)st[p][j] * 128 + c];
    // bottom-up heap accumulation: node i += children 2i+1, 2i+2
    #pragma unroll
    for (int i = 14; i >= 0; --i)
        v[i] += v[2 * i + 1] + v[2 * i + 2];

    const float wb = Wcb[c];
    float m = v[0] + 31.f * wb;
    #pragma unroll
    for (int i = 1; i <= 2; ++i)  m = fmaxf(m, v[i] + 15.f * wb);
    #pragma unroll
    for (int i = 3; i <= 6; ++i)  m = fmaxf(m, v[i] + 7.f * wb);
    #pragma unroll
    for (int i = 7; i <= 14; ++i) m = fmaxf(m, v[i] + 3.f * wb);
    #pragma unroll
    for (int i = 15; i <= 30; ++i) m = fmaxf(m, v[i] + wb);

    enc[(size_t)(bl + p) * 128 + c] = m;
}

// ---------------------------------------------------------------------------
// GRU scan: one block per (direction, batch-row) chain = 128 blocks.
// 384 threads; thread g owns gate-row g: Whh[g,0:128] held in 32 float4 VGPRs.
// h lives in LDS (broadcast reads); only running max over t is kept.
// ---------------------------------------------------------------------------
__device__ __forceinline__ float sigm(float x) { return 1.f / (1.f + __expf(-x)); }
__device__ __forceinline__ float tanh_f(float x) { return 1.f - 2.f / (1.f + __expf(2.f * x)); }

__global__ __launch_bounds__(384, 1) void gru_scan(const float* __restrict__ gi_f,
                                                   const float* __restrict__ gi_b,
                                                   const float* __restrict__ Whh_f,
                                                   const float* __restrict__ Whh_b,
                                                   const float* __restrict__ bhh_f,
                                                   const float* __restrict__ bhh_b,
                                                   float* __restrict__ pooled) {
    const int g = threadIdx.x;           // 0..383
    const int dir = blockIdx.x & 1;
    const int b = blockIdx.x >> 1;
    const float* gi  = dir ? gi_b  : gi_f;
    const float* Whh = dir ? Whh_b : Whh_f;
    const float* bhh = dir ? bhh_b : bhh_f;

    __shared__ __align__(16) float h[128];
    __shared__ float sz[128], shn[128], sinn[128];

    float4 w[32];
    const float4* wf4 = (const float4*)Whh;
    #pragma unroll
    for (int q = 0; q < 32; ++q) w[q] = wf4[(size_t)g * 32 + q];
    const float bh = bhh[g];
    if (g < 128) h[g] = 0.f;
    float m = -INFINITY;
    __syncthreads();

    const float4* hf4 = (const float4*)h;
    for (int s = 0; s < LL; ++s) {
        const int t = dir ? (LL - 1 - s) : s;
        const float gv = gi[((size_t)b * LL + t) * 384 + g];

        float acc = bh;                  // gh_g = Whh[g,:]·h + bhh[g]
        #pragma unroll
        for (int q = 0; q < 32; ++q) {
            float4 hv = hf4[q];
            acc += w[q].x * hv.x + w[q].y * hv.y + w[q].z * hv.z + w[q].w * hv.w;
        }

        float r = 0.f, hold = 0.f;
        if (g < 128) {                   // r-gate rows (waves 0-1)
            r = sigm(gv + acc);
            hold = h[g];
        } else if (g < 256) {            // z-gate rows (waves 2-3)
            sz[g - 128] = sigm(gv + acc);
        } else {                         // n-gate rows (waves 4-5)
            shn[g - 256] = acc;
            sinn[g - 256] = gv;
        }
        __syncthreads();                 // gates visible; matvec reads done
        if (g < 128) {
            float n = tanh_f(sinn[g] + r * shn[g]);
            float z = sz[g];
            float hn = (1.f - z) * n + z * hold;
            h[g] = hn;
            m = fmaxf(m, hn);
        }
        __syncthreads();                 // h ready for next step
    }
    if (g < 128) pooled[((size_t)b * 2 + dir) * 128 + g] = m;
}

// ---------------------------------------------------------------------------
// Output head: out[b,o] = pooled[b,:]·Wout[o,:] + bout[o]   (64 x 104 x 256)
// ---------------------------------------------------------------------------
__global__ __launch_bounds__(128) void out_head(const float* __restrict__ pooled,
                                                const float* __restrict__ Wout,
                                                const float* __restrict__ bout,
                                                float* __restrict__ out) {
    __shared__ __align__(16) float p[256];
    const int b = blockIdx.x, o = threadIdx.x;
    if (o < 64) ((float4*)p)[o] = ((const float4*)(pooled + (size_t)b * 256))[o];
    __syncthreads();
    if (o < NLBL) {
        float acc = bout[o];
        const float4* wf4 = (const float4*)(Wout + (size_t)o * 256);
        const float4* pf4 = (const float4*)p;
        #pragma unroll 8
        for (int q = 0; q < 64; ++q) {
            float4 wv = wf4[q], pv = pf4[q];
            acc += wv.x * pv.x + wv.y * pv.y + wv.z * pv.z + wv.w * pv.w;
        }
        out[(size_t)b * NLBL + o] = acc;
    }
}

// ---------------------------------------------------------------------------
extern "C" void kernel_launch(void* const* d_in, const int* in_sizes, int n_in,
                              void* d_out, int out_size, void* d_ws, size_t ws_size,
                              hipStream_t stream) {
    const int*   tokens = (const int*)  d_in[0];
    const float* emb    = (const float*)d_in[1];
    const float* Wc_w   = (const float*)d_in[2];
    const float* Wc_b   = (const float*)d_in[3];
    const float* Wih_f  = (const float*)d_in[4];
    const float* Whh_f  = (const float*)d_in[5];
    const float* bih_f  = (const float*)d_in[6];
    const float* bhh_f  = (const float*)d_in[7];
    const float* Wih_b  = (const float*)d_in[8];
    const float* Whh_b  = (const float*)d_in[9];
    const float* bih_b  = (const float*)d_in[10];
    const float* bhh_b  = (const float*)d_in[11];
    const float* Wout   = (const float*)d_in[12];
    const float* bout   = (const float*)d_in[13];
    float* out = (float*)d_out;
    float* ws  = (float*)d_ws;

    // workspace layout (floats)
    float* Wemb = ws;                                   // 50000*128 = 6.40M
    float* enc  = Wemb + (size_t)VV * 128;              // 8192*128  = 1.05M
    float* gi_f = enc  + (size_t)BB * LL * 128;         // 8192*384  = 3.15M
    float* gi_b = gi_f + (size_t)BB * LL * 384;         // 8192*384  = 3.15M
    float* pool = gi_b + (size_t)BB * LL * 384;         // 64*256
    // total ~55 MB

    // 1. projected embedding table: Wemb = emb @ Wc_w^T  (1.64 GFLOP)
    gemm128<false><<<dim3(782, 1), 256, 0, stream>>>(emb, Wc_w, nullptr, Wemb, VV, 128);
    // 2. gather + tree-sum + node-max -> encodes (8192 x 128)
    tree_encode<<<dim3(4096), 256, 0, stream>>>(tokens, Wemb, Wc_b, enc);
    // 3. input gates for both directions (2 x 0.8 GFLOP)
    gemm128<true><<<dim3(128, 3), 256, 0, stream>>>(enc, Wih_f, bih_f, gi_f, BB * LL, 384);
    gemm128<true><<<dim3(128, 3), 256, 0, stream>>>(enc, Wih_b, bih_b, gi_b, BB * LL, 384);
    // 4. sequential GRU scans, 128 independent chains, fused max-pool over t
    gru_scan<<<dim3(128), 384, 0, stream>>>(gi_f, gi_b, Whh_f, Whh_b, bhh_f, bhh_b, pool);
    // 5. output head
    out_head<<<dim3(64), 128, 0, stream>>>(pool, Wout, bout, out);
}

// Round 3
// 295.197 us; speedup vs baseline: 1.1014x; 1.1014x over previous
//
#include <hip/hip_runtime.h>
#include <hip/hip_bf16.h>
#include <math.h>

// Problem constants (from reference)
#define NN   31      // tree nodes
#define VV   50000   // vocab
#define EE   128     // embed = enc = H = 128
#define HH   128
#define BB   64
#define LL   128
#define NLBL 104

// ---------------------------------------------------------------------------
// Generic fp32 GEMM: C[M,N] = A[M,128] * B[N,128]^T (+ bias[N])
// Tile 64x128, 256 threads, K split in 2 halves of 64 so LDS stays < 64KB.
// gridDim.z indexes a (B, bias, C) set -> fuses sibling GEMMs sharing A.
// ---------------------------------------------------------------------------
template <bool BIAS>
__global__ __launch_bounds__(256, 2) void gemm128(const float* __restrict__ A,
                                                  const float* __restrict__ B0,
                                                  const float* __restrict__ B1,
                                                  const float* __restrict__ bias0,
                                                  const float* __restrict__ bias1,
                                                  float* __restrict__ C0,
                                                  float* __restrict__ C1,
                                                  int M, int N) {
    const float* Bm  = blockIdx.z ? B1 : B0;
    const float* bias = blockIdx.z ? bias1 : bias0;
    float* C = blockIdx.z ? C1 : C0;

    __shared__ float4 As[64 * 17];
    __shared__ float4 Bs[128 * 17];
    const int tid = threadIdx.x;
    const int m0 = blockIdx.x * 64;
    const int n0 = blockIdx.y * 128;
    const float4* Af4 = (const float4*)A;
    const float4* Bf4 = (const float4*)Bm;

    const int r0 = (tid >> 4) * 4;
    const int cb = tid & 15;
    float acc[4][8] = {};

    for (int kk = 0; kk < 2; ++kk) {
        for (int f = tid; f < 128 * 16; f += 256) {
            int r = f >> 4, e = f & 15;
            Bs[r * 17 + e] = Bf4[(size_t)(n0 + r) * 32 + kk * 16 + e];
        }
        for (int f = tid; f < 64 * 16; f += 256) {
            int r = f >> 4, e = f & 15;
            float4 v = make_float4(0.f, 0.f, 0.f, 0.f);
            if (m0 + r < M) v = Af4[(size_t)(m0 + r) * 32 + kk * 16 + e];
            As[r * 17 + e] = v;
        }
        __syncthreads();
        #pragma unroll
        for (int e = 0; e < 16; ++e) {
            float4 a[4], b[8];
            #pragma unroll
            for (int i = 0; i < 4; ++i) a[i] = As[(r0 + i) * 17 + e];
            #pragma unroll
            for (int j = 0; j < 8; ++j) b[j] = Bs[(cb + j * 16) * 17 + e];
            #pragma unroll
            for (int i = 0; i < 4; ++i) {
                #pragma unroll
                for (int j = 0; j < 8; ++j) {
                    acc[i][j] += a[i].x * b[j].x;
                    acc[i][j] += a[i].y * b[j].y;
                    acc[i][j] += a[i].z * b[j].z;
                    acc[i][j] += a[i].w * b[j].w;
                }
            }
        }
        __syncthreads();
    }

    #pragma unroll
    for (int i = 0; i < 4; ++i) {
        int row = m0 + r0 + i;
        if (row < M) {
            #pragma unroll
            for (int j = 0; j < 8; ++j) {
                int col = n0 + cb + j * 16;
                float v = acc[i][j];
                if (BIAS) v += bias[col];
                C[(size_t)row * N + col] = v;
            }
        }
    }
}

// ---------------------------------------------------------------------------
// Tree encode: gather 31 projected rows, heap-sum in regs, node-max.
// ---------------------------------------------------------------------------
__global__ __launch_bounds__(256) void tree_encode(const int* __restrict__ tok,
                                                   const float* __restrict__ Wemb,
                                                   const float* __restrict__ Wcb,
                                                   float* __restrict__ enc) {
    __shared__ int st[2][NN];
    const int tid = threadIdx.x;
    const int p = tid >> 7;
    const int c = tid & 127;
    const int bl = blockIdx.x * 2;
    if (tid < 2 * NN) {
        int pp = tid / NN, jj = tid - pp * NN;
        st[pp][jj] = tok[(size_t)(bl + pp) * NN + jj];
    }
    __syncthreads();

    float v[NN];
    #pragma unroll
    for (int j = 0; j < NN; ++j)
        v[j] = Wemb[(size_t)st[p][j] * 128 + c];
    #pragma unroll
    for (int i = 14; i >= 0; --i)
        v[i] += v[2 * i + 1] + v[2 * i + 2];

    const float wb = Wcb[c];
    float m = v[0] + 31.f * wb;
    #pragma unroll
    for (int i = 1; i <= 2; ++i)  m = fmaxf(m, v[i] + 15.f * wb);
    #pragma unroll
    for (int i = 3; i <= 6; ++i)  m = fmaxf(m, v[i] + 7.f * wb);
    #pragma unroll
    for (int i = 7; i <= 14; ++i) m = fmaxf(m, v[i] + 3.f * wb);
    #pragma unroll
    for (int i = 15; i <= 30; ++i) m = fmaxf(m, v[i] + wb);

    enc[(size_t)(bl + p) * 128 + c] = m;
}

// ---------------------------------------------------------------------------
// GRU scan v2: 256 threads = 64 groups x 4 k-quarters. Group g owns channels
// {g, g+64}, all 3 gates; thread (g,p) holds Whh[r6*64+g, p*32..+32) in VGPRs
// (48 f4). Quarter partial sums combined via DPP quad_perm (pure VALU).
// h double-buffered in LDS -> ONE barrier/step. gi prefetched one step ahead.
// ---------------------------------------------------------------------------
__device__ __forceinline__ float sigm(float x) { return 1.f / (1.f + __expf(-x)); }
__device__ __forceinline__ float tanh_f(float x) { return 1.f - 2.f / (1.f + __expf(2.f * x)); }

__device__ __forceinline__ float dpp_xor1(float x) {
    return __builtin_bit_cast(float,
        __builtin_amdgcn_mov_dpp(__builtin_bit_cast(int, x), 0xB1, 0xF, 0xF, true));
}
__device__ __forceinline__ float dpp_xor2(float x) {
    return __builtin_bit_cast(float,
        __builtin_amdgcn_mov_dpp(__builtin_bit_cast(int, x), 0x4E, 0xF, 0xF, true));
}
__device__ __forceinline__ float quad_sum(float x) {
    x += dpp_xor1(x);
    x += dpp_xor2(x);
    return x;   // all 4 lanes of the quad hold the full sum
}

__global__ __launch_bounds__(256, 1) void gru_scan(const float* __restrict__ gi_f,
                                                   const float* __restrict__ gi_b,
                                                   const float* __restrict__ Whh_f,
                                                   const float* __restrict__ Whh_b,
                                                   const float* __restrict__ bhh_f,
                                                   const float* __restrict__ bhh_b,
                                                   float* __restrict__ pooled) {
    const int tid = threadIdx.x;
    const int g   = tid >> 2;     // group 0..63
    const int p   = tid & 3;      // k-quarter 0..3
    const int dir = blockIdx.x & 1;
    const int b   = blockIdx.x >> 1;
    const float* gi  = dir ? gi_b  : gi_f;
    const float* Whh = dir ? Whh_b : Whh_f;
    const float* bhh = dir ? bhh_b : bhh_f;

    __shared__ __align__(16) float hbuf[2][128];

    // weights: rows r6*64+g (r6=0..5 -> {r,r+64,z,z+64,n,n+64}), k quarter p
    float4 w[6][8];
    const float4* wf4 = (const float4*)Whh;
    #pragma unroll
    for (int r6 = 0; r6 < 6; ++r6)
        #pragma unroll
        for (int q = 0; q < 8; ++q)
            w[r6][q] = wf4[(size_t)(r6 * 64 + g) * 32 + p * 8 + q];

    // lanes p<2 own channel c = g + p*64 (gate combine + h write)
    const int c = g + p * 64;
    float bh_r = 0.f, bh_z = 0.f, bh_n = 0.f;
    if (p < 2) { bh_r = bhh[c]; bh_z = bhh[128 + c]; bh_n = bhh[256 + c]; }

    float hold = 0.f, m = -INFINITY;
    if (tid < 128) { hbuf[0][tid] = 0.f; }

    // prefetch gi for step 0
    float gr = 0.f, gz = 0.f, gn = 0.f;
    {
        const int t0 = dir ? (LL - 1) : 0;
        const float* grow = gi + ((size_t)b * LL + t0) * 384;
        if (p < 2) { gr = grow[c]; gz = grow[128 + c]; gn = grow[256 + c]; }
    }
    __syncthreads();

    for (int s = 0; s < LL; ++s) {
        const int cur = s & 1;
        // prefetch next step's gi (independent of h -> hidden under matvec)
        float gr_n = 0.f, gz_n = 0.f, gn_n = 0.f;
        if (p < 2 && s + 1 < LL) {
            const int t1 = dir ? (LL - 2 - s) : (s + 1);
            const float* grow = gi + ((size_t)b * LL + t1) * 384;
            gr_n = grow[c]; gz_n = grow[128 + c]; gn_n = grow[256 + c];
        }

        // partial matvec over this thread's k-quarter (6 independent chains)
        const float4* hq = ((const float4*)hbuf[cur]) + p * 8;
        float a0 = 0.f, a1 = 0.f, a2 = 0.f, a3 = 0.f, a4 = 0.f, a5 = 0.f;
        #pragma unroll
        for (int q = 0; q < 8; ++q) {
            const float4 hv = hq[q];
            a0 += w[0][q].x * hv.x + w[0][q].y * hv.y + w[0][q].z * hv.z + w[0][q].w * hv.w;
            a1 += w[1][q].x * hv.x + w[1][q].y * hv.y + w[1][q].z * hv.z + w[1][q].w * hv.w;
            a2 += w[2][q].x * hv.x + w[2][q].y * hv.y + w[2][q].z * hv.z + w[2][q].w * hv.w;
            a3 += w[3][q].x * hv.x + w[3][q].y * hv.y + w[3][q].z * hv.z + w[3][q].w * hv.w;
            a4 += w[4][q].x * hv.x + w[4][q].y * hv.y + w[4][q].z * hv.z + w[4][q].w * hv.w;
            a5 += w[5][q].x * hv.x + w[5][q].y * hv.y + w[5][q].z * hv.z + w[5][q].w * hv.w;
        }
        // combine the 4 k-quarters within the quad (all lanes get full sums)
        a0 = quad_sum(a0); a1 = quad_sum(a1); a2 = quad_sum(a2);
        a3 = quad_sum(a3); a4 = quad_sum(a4); a5 = quad_sum(a5);

        if (p < 2) {
            const float ghr = (p ? a1 : a0) + bh_r;
            const float ghz = (p ? a3 : a2) + bh_z;
            const float ghn = (p ? a5 : a4) + bh_n;
            const float r = sigm(gr + ghr);
            const float z = sigm(gz + ghz);
            const float n = tanh_f(gn + r * ghn);
            const float hn = (1.f - z) * n + z * hold;
            hold = hn;
            m = fmaxf(m, hn);
            hbuf[cur ^ 1][c] = hn;
        }
        gr = gr_n; gz = gz_n; gn = gn_n;
        __syncthreads();   // publish hbuf[cur^1] for next step
    }
    if (p < 2) pooled[((size_t)b * 2 + dir) * 128 + c] = m;
}

// ---------------------------------------------------------------------------
// Output head: out[b,o] = pooled[b,:]·Wout[o,:] + bout[o]   (64 x 104 x 256)
// ---------------------------------------------------------------------------
__global__ __launch_bounds__(128) void out_head(const float* __restrict__ pooled,
                                                const float* __restrict__ Wout,
                                                const float* __restrict__ bout,
                                                float* __restrict__ out) {
    __shared__ __align__(16) float pbuf[256];
    const int b = blockIdx.x, o = threadIdx.x;
    if (o < 64) ((float4*)pbuf)[o] = ((const float4*)(pooled + (size_t)b * 256))[o];
    __syncthreads();
    if (o < NLBL) {
        float acc = bout[o];
        const float4* wf4 = (const float4*)(Wout + (size_t)o * 256);
        const float4* pf4 = (const float4*)pbuf;
        #pragma unroll 8
        for (int q = 0; q < 64; ++q) {
            float4 wv = wf4[q], pv = pf4[q];
            acc += wv.x * pv.x + wv.y * pv.y + wv.z * pv.z + wv.w * pv.w;
        }
        out[(size_t)b * NLBL + o] = acc;
    }
}

// ---------------------------------------------------------------------------
extern "C" void kernel_launch(void* const* d_in, const int* in_sizes, int n_in,
                              void* d_out, int out_size, void* d_ws, size_t ws_size,
                              hipStream_t stream) {
    const int*   tokens = (const int*)  d_in[0];
    const float* emb    = (const float*)d_in[1];
    const float* Wc_w   = (const float*)d_in[2];
    const float* Wc_b   = (const float*)d_in[3];
    const float* Wih_f  = (const float*)d_in[4];
    const float* Whh_f  = (const float*)d_in[5];
    const float* bih_f  = (const float*)d_in[6];
    const float* bhh_f  = (const float*)d_in[7];
    const float* Wih_b  = (const float*)d_in[8];
    const float* Whh_b  = (const float*)d_in[9];
    const float* bih_b  = (const float*)d_in[10];
    const float* bhh_b  = (const float*)d_in[11];
    const float* Wout   = (const float*)d_in[12];
    const float* bout   = (const float*)d_in[13];
    float* out = (float*)d_out;
    float* ws  = (float*)d_ws;

    float* Wemb = ws;                                   // 50000*128
    float* enc  = Wemb + (size_t)VV * 128;              // 8192*128
    float* gi_f = enc  + (size_t)BB * LL * 128;         // 8192*384
    float* gi_b = gi_f + (size_t)BB * LL * 384;         // 8192*384
    float* pool = gi_b + (size_t)BB * LL * 384;         // 64*256

    // 1. projected embedding table: Wemb = emb @ Wc_w^T  (1.64 GFLOP)
    gemm128<false><<<dim3(782, 1, 1), 256, 0, stream>>>(
        emb, Wc_w, Wc_w, nullptr, nullptr, Wemb, Wemb, VV, 128);
    // 2. gather + tree-sum + node-max -> encodes (8192 x 128)
    tree_encode<<<dim3(4096), 256, 0, stream>>>(tokens, Wemb, Wc_b, enc);
    // 3. input gates, both directions in ONE dispatch (z selects dir)
    gemm128<true><<<dim3(128, 3, 2), 256, 0, stream>>>(
        enc, Wih_f, Wih_b, bih_f, bih_b, gi_f, gi_b, BB * LL, 384);
    // 4. sequential GRU scans, 128 independent chains, fused max-pool over t
    gru_scan<<<dim3(128), 256, 0, stream>>>(gi_f, gi_b, Whh_f, Whh_b, bhh_f, bhh_b, pool);
    // 5. output head
    out_head<<<dim3(64), 128, 0, stream>>>(pool, Wout, bout, out);
}

// Round 6
// 284.189 us; speedup vs baseline: 1.1441x; 1.0387x over previous
//
#include <hip/hip_runtime.h>
#include <hip/hip_bf16.h>
#include <math.h>

// Problem constants (from reference)
#define NN   31      // tree nodes
#define VV   50000   // vocab
#define EE   128     // embed = enc = H = 128
#define HH   128
#define BB   64
#define LL   128
#define NLBL 104

// ---------------------------------------------------------------------------
// Generic fp32 GEMM: C[M,N] = A[M,128] * B[N,128]^T (+ bias[N])
// Tile 64x128, 256 threads, K split in 2 halves of 64 so LDS stays < 64KB.
// gridDim.z indexes a (B, bias, C) set -> fuses sibling GEMMs sharing A.
// ---------------------------------------------------------------------------
template <bool BIAS>
__global__ __launch_bounds__(256, 2) void gemm128(const float* __restrict__ A,
                                                  const float* __restrict__ B0,
                                                  const float* __restrict__ B1,
                                                  const float* __restrict__ bias0,
                                                  const float* __restrict__ bias1,
                                                  float* __restrict__ C0,
                                                  float* __restrict__ C1,
                                                  int M, int N) {
    const float* Bm  = blockIdx.z ? B1 : B0;
    const float* bias = blockIdx.z ? bias1 : bias0;
    float* C = blockIdx.z ? C1 : C0;

    __shared__ float4 As[64 * 17];
    __shared__ float4 Bs[128 * 17];
    const int tid = threadIdx.x;
    const int m0 = blockIdx.x * 64;
    const int n0 = blockIdx.y * 128;
    const float4* Af4 = (const float4*)A;
    const float4* Bf4 = (const float4*)Bm;

    const int r0 = (tid >> 4) * 4;
    const int cb = tid & 15;
    float acc[4][8] = {};

    for (int kk = 0; kk < 2; ++kk) {
        for (int f = tid; f < 128 * 16; f += 256) {
            int r = f >> 4, e = f & 15;
            Bs[r * 17 + e] = Bf4[(size_t)(n0 + r) * 32 + kk * 16 + e];
        }
        for (int f = tid; f < 64 * 16; f += 256) {
            int r = f >> 4, e = f & 15;
            float4 v = make_float4(0.f, 0.f, 0.f, 0.f);
            if (m0 + r < M) v = Af4[(size_t)(m0 + r) * 32 + kk * 16 + e];
            As[r * 17 + e] = v;
        }
        __syncthreads();
        #pragma unroll
        for (int e = 0; e < 16; ++e) {
            float4 a[4], b[8];
            #pragma unroll
            for (int i = 0; i < 4; ++i) a[i] = As[(r0 + i) * 17 + e];
            #pragma unroll
            for (int j = 0; j < 8; ++j) b[j] = Bs[(cb + j * 16) * 17 + e];
            #pragma unroll
            for (int i = 0; i < 4; ++i) {
                #pragma unroll
                for (int j = 0; j < 8; ++j) {
                    acc[i][j] += a[i].x * b[j].x;
                    acc[i][j] += a[i].y * b[j].y;
                    acc[i][j] += a[i].z * b[j].z;
                    acc[i][j] += a[i].w * b[j].w;
                }
            }
        }
        __syncthreads();
    }

    #pragma unroll
    for (int i = 0; i < 4; ++i) {
        int row = m0 + r0 + i;
        if (row < M) {
            #pragma unroll
            for (int j = 0; j < 8; ++j) {
                int col = n0 + cb + j * 16;
                float v = acc[i][j];
                if (BIAS) v += bias[col];
                C[(size_t)row * N + col] = v;
            }
        }
    }
}

// ---------------------------------------------------------------------------
// Tree encode: gather 31 projected rows, heap-sum in regs, node-max.
// ---------------------------------------------------------------------------
__global__ __launch_bounds__(256) void tree_encode(const int* __restrict__ tok,
                                                   const float* __restrict__ Wemb,
                                                   const float* __restrict__ Wcb,
                                                   float* __restrict__ enc) {
    __shared__ int st[2][NN];
    const int tid = threadIdx.x;
    const int p = tid >> 7;
    const int c = tid & 127;
    const int bl = blockIdx.x * 2;
    if (tid < 2 * NN) {
        int pp = tid / NN, jj = tid - pp * NN;
        st[pp][jj] = tok[(size_t)(bl + pp) * NN + jj];
    }
    __syncthreads();

    float v[NN];
    #pragma unroll
    for (int j = 0; j < NN; ++j)
        v[j] = Wemb[(size_t)st[p][j] * 128 + c];
    #pragma unroll
    for (int i = 14; i >= 0; --i)
        v[i] += v[2 * i + 1] + v[2 * i + 2];

    const float wb = Wcb[c];
    float m = v[0] + 31.f * wb;
    #pragma unroll
    for (int i = 1; i <= 2; ++i)  m = fmaxf(m, v[i] + 15.f * wb);
    #pragma unroll
    for (int i = 3; i <= 6; ++i)  m = fmaxf(m, v[i] + 7.f * wb);
    #pragma unroll
    for (int i = 7; i <= 14; ++i) m = fmaxf(m, v[i] + 3.f * wb);
    #pragma unroll
    for (int i = 15; i <= 30; ++i) m = fmaxf(m, v[i] + wb);

    enc[(size_t)(bl + p) * 128 + c] = m;
}

// ---------------------------------------------------------------------------
// GRU scan v5 = v4 with the grid bug fixed: 128 chains (64 batch x 2 dir)
// need 128 BLOCKS (v3/v4 launched 64 -> b=0..31 only; pooled[b>=32] kept its
// ~0 poison -> deterministic absmax 6.7e-2, identical across sync variants,
// which disproved the round-4 race theory).
// 512 threads = 128 channels x 4 k-quarters, one chain per block, 8 waves.
// Thread (c,p) holds Whh rows {c,128+c,256+c} over quarter p = 24 float4 =
// 96 floats -> register-resident (v2's 192-float footprint made the compiler
// re-load weights from L2 every step: VGPR_Count=116, ~29 TB/s L2 traffic).
// Bank-conflict fix: k-chunk order rotated by 2p -> the 4 p-lanes of a quad
// hit 4 distinct bank quads each slot; cross-quad aliases are same-address
// broadcasts (free).
// ---------------------------------------------------------------------------
__device__ __forceinline__ float sigm(float x) { return 1.f / (1.f + __expf(-x)); }
__device__ __forceinline__ float tanh_f(float x) { return 1.f - 2.f / (1.f + __expf(2.f * x)); }

__device__ __forceinline__ float dpp_xor1(float x) {
    return __builtin_bit_cast(float,
        __builtin_amdgcn_mov_dpp(__builtin_bit_cast(int, x), 0xB1, 0xF, 0xF, true));
}
__device__ __forceinline__ float dpp_xor2(float x) {
    return __builtin_bit_cast(float,
        __builtin_amdgcn_mov_dpp(__builtin_bit_cast(int, x), 0x4E, 0xF, 0xF, true));
}
__device__ __forceinline__ float quad_sum(float x) {
    x += dpp_xor1(x);
    x += dpp_xor2(x);
    return x;   // all 4 lanes of the quad hold the full sum
}

__global__ __launch_bounds__(512, 1) void gru_scan(const float* __restrict__ gi_f,
                                                   const float* __restrict__ gi_b,
                                                   const float* __restrict__ Whh_f,
                                                   const float* __restrict__ Whh_b,
                                                   const float* __restrict__ bhh_f,
                                                   const float* __restrict__ bhh_b,
                                                   float* __restrict__ pooled) {
    const int tid = threadIdx.x;
    const int c   = tid >> 2;     // channel 0..127
    const int p   = tid & 3;      // k-quarter 0..3
    const int dir = blockIdx.x & 1;
    const int b   = blockIdx.x >> 1;   // 0..63 with 128 blocks
    const float* gi  = dir ? gi_b  : gi_f;
    const float* Whh = dir ? Whh_b : Whh_f;
    const float* bhh = dir ? bhh_b : bhh_f;

    __shared__ __align__(16) float hbuf[2][128];

    // weights, k-chunk order rotated by 2p (bank-conflict-free LDS reads):
    // w[r][i] corresponds to k-chunk p*8 + ((i+2p)&7)
    float4 w[3][8];
    const float4* wf4 = (const float4*)Whh;
    #pragma unroll
    for (int r = 0; r < 3; ++r)
        #pragma unroll
        for (int i = 0; i < 8; ++i)
            w[r][i] = wf4[(size_t)(r * 128 + c) * 32 + p * 8 + ((i + 2 * p) & 7)];

    float bh_r = 0.f, bh_z = 0.f, bh_n = 0.f;
    if (p == 0) { bh_r = bhh[c]; bh_z = bhh[128 + c]; bh_n = bhh[256 + c]; }

    float hold = 0.f, m = -INFINITY;
    if (tid < 128) hbuf[0][tid] = 0.f;

    // prefetch gi for steps 0 and 1 (p==0 lanes only)
    float g0r = 0.f, g0z = 0.f, g0n = 0.f, g1r = 0.f, g1z = 0.f, g1n = 0.f;
    if (p == 0) {
        const float* row0 = gi + ((size_t)b * LL + (dir ? LL - 1 : 0)) * 384;
        g0r = row0[c]; g0z = row0[128 + c]; g0n = row0[256 + c];
        const float* row1 = gi + ((size_t)b * LL + (dir ? LL - 2 : 1)) * 384;
        g1r = row1[c]; g1z = row1[128 + c]; g1n = row1[256 + c];
    }
    __syncthreads();   // publish hbuf[0]

    for (int s = 0; s < LL; ++s) {
        const int cur = s & 1;
        // prefetch gi for step s+2
        float g2r = 0.f, g2z = 0.f, g2n = 0.f;
        if (p == 0 && s + 2 < LL) {
            const int t2 = dir ? (LL - 3 - s) : (s + 2);
            const float* row = gi + ((size_t)b * LL + t2) * 384;
            g2r = row[c]; g2z = row[128 + c]; g2n = row[256 + c];
        }

        // partial matvec over this thread's k-quarter, rotated chunk order
        const float4* hq = (const float4*)hbuf[cur];
        float a0 = 0.f, a1 = 0.f, a2 = 0.f;
        #pragma unroll
        for (int i = 0; i < 8; ++i) {
            const float4 hv = hq[p * 8 + ((i + 2 * p) & 7)];
            a0 += w[0][i].x * hv.x + w[0][i].y * hv.y + w[0][i].z * hv.z + w[0][i].w * hv.w;
            a1 += w[1][i].x * hv.x + w[1][i].y * hv.y + w[1][i].z * hv.z + w[1][i].w * hv.w;
            a2 += w[2][i].x * hv.x + w[2][i].y * hv.y + w[2][i].z * hv.z + w[2][i].w * hv.w;
        }
        a0 = quad_sum(a0); a1 = quad_sum(a1); a2 = quad_sum(a2);

        if (p == 0) {
            const float r = sigm(g0r + a0 + bh_r);
            const float z = sigm(g0z + a1 + bh_z);
            const float n = tanh_f(g0n + r * (a2 + bh_n));
            const float hn = (1.f - z) * n + z * hold;
            hold = hn;
            m = fmaxf(m, hn);
            hbuf[cur ^ 1][c] = hn;
        }
        g0r = g1r; g0z = g1z; g0n = g1n;
        g1r = g2r; g1z = g2z; g1n = g2n;
        __syncthreads();   // publish hbuf[cur^1] for next step
    }
    if (p == 0) pooled[((size_t)b * 2 + dir) * 128 + c] = m;
}

// ---------------------------------------------------------------------------
// Output head: out[b,o] = pooled[b,:]·Wout[o,:] + bout[o]   (64 x 104 x 256)
// ---------------------------------------------------------------------------
__global__ __launch_bounds__(128) void out_head(const float* __restrict__ pooled,
                                                const float* __restrict__ Wout,
                                                const float* __restrict__ bout,
                                                float* __restrict__ out) {
    __shared__ __align__(16) float pbuf[256];
    const int b = blockIdx.x, o = threadIdx.x;
    if (o < 64) ((float4*)pbuf)[o] = ((const float4*)(pooled + (size_t)b * 256))[o];
    __syncthreads();
    if (o < NLBL) {
        float acc = bout[o];
        const float4* wf4 = (const float4*)(Wout + (size_t)o * 256);
        const float4* pf4 = (const float4*)pbuf;
        #pragma unroll 8
        for (int q = 0; q < 64; ++q) {
            float4 wv = wf4[q], pv = pf4[q];
            acc += wv.x * pv.x + wv.y * pv.y + wv.z * pv.z + wv.w * pv.w;
        }
        out[(size_t)b * NLBL + o] = acc;
    }
}

// ---------------------------------------------------------------------------
extern "C" void kernel_launch(void* const* d_in, const int* in_sizes, int n_in,
                              void* d_out, int out_size, void* d_ws, size_t ws_size,
                              hipStream_t stream) {
    const int*   tokens = (const int*)  d_in[0];
    const float* emb    = (const float*)d_in[1];
    const float* Wc_w   = (const float*)d_in[2];
    const float* Wc_b   = (const float*)d_in[3];
    const float* Wih_f  = (const float*)d_in[4];
    const float* Whh_f  = (const float*)d_in[5];
    const float* bih_f  = (const float*)d_in[6];
    const float* bhh_f  = (const float*)d_in[7];
    const float* Wih_b  = (const float*)d_in[8];
    const float* Whh_b  = (const float*)d_in[9];
    const float* bih_b  = (const float*)d_in[10];
    const float* bhh_b  = (const float*)d_in[11];
    const float* Wout   = (const float*)d_in[12];
    const float* bout   = (const float*)d_in[13];
    float* out = (float*)d_out;
    float* ws  = (float*)d_ws;

    float* Wemb = ws;                                   // 50000*128
    float* enc  = Wemb + (size_t)VV * 128;              // 8192*128
    float* gi_f = enc  + (size_t)BB * LL * 128;         // 8192*384
    float* gi_b = gi_f + (size_t)BB * LL * 384;         // 8192*384
    float* pool = gi_b + (size_t)BB * LL * 384;         // 64*256

    // 1. projected embedding table: Wemb = emb @ Wc_w^T  (1.64 GFLOP)
    gemm128<false><<<dim3(782, 1, 1), 256, 0, stream>>>(
        emb, Wc_w, Wc_w, nullptr, nullptr, Wemb, Wemb, VV, 128);
    // 2. gather + tree-sum + node-max -> encodes (8192 x 128)
    tree_encode<<<dim3(4096), 256, 0, stream>>>(tokens, Wemb, Wc_b, enc);
    // 3. input gates, both directions in ONE dispatch (z selects dir)
    gemm128<true><<<dim3(128, 3, 2), 256, 0, stream>>>(
        enc, Wih_f, Wih_b, bih_f, bih_b, gi_f, gi_b, BB * LL, 384);
    // 4. sequential GRU scans: 128 chains (64 b x 2 dir) -> 128 BLOCKS
    gru_scan<<<dim3(128), 512, 0, stream>>>(gi_f, gi_b, Whh_f, Whh_b, bhh_f, bhh_b, pool);
    // 5. output head
    out_head<<<dim3(64), 128, 0, stream>>>(pool, Wout, bout, out);
}

// Round 7
// 283.923 us; speedup vs baseline: 1.1451x; 1.0009x over previous
//
#include <hip/hip_runtime.h>
#include <hip/hip_bf16.h>
#include <math.h>

// Problem constants (from reference)
#define NN   31      // tree nodes
#define VV   50000   // vocab
#define EE   128     // embed = enc = H = 128
#define HH   128
#define BB   64
#define LL   128
#define NLBL 104

// ---------------------------------------------------------------------------
// Generic fp32 GEMM: C[M,N] = A[M,128] * B[N,128]^T (+ bias[N])
// Tile 64x128, 256 threads, K split in 2 halves of 64 so LDS stays < 64KB.
// gridDim.z indexes a (B, bias, C) set -> fuses sibling GEMMs sharing A.
// ---------------------------------------------------------------------------
template <bool BIAS>
__global__ __launch_bounds__(256, 2) void gemm128(const float* __restrict__ A,
                                                  const float* __restrict__ B0,
                                                  const float* __restrict__ B1,
                                                  const float* __restrict__ bias0,
                                                  const float* __restrict__ bias1,
                                                  float* __restrict__ C0,
                                                  float* __restrict__ C1,
                                                  int M, int N) {
    const float* Bm  = blockIdx.z ? B1 : B0;
    const float* bias = blockIdx.z ? bias1 : bias0;
    float* C = blockIdx.z ? C1 : C0;

    __shared__ float4 As[64 * 17];
    __shared__ float4 Bs[128 * 17];
    const int tid = threadIdx.x;
    const int m0 = blockIdx.x * 64;
    const int n0 = blockIdx.y * 128;
    const float4* Af4 = (const float4*)A;
    const float4* Bf4 = (const float4*)Bm;

    const int r0 = (tid >> 4) * 4;
    const int cb = tid & 15;
    float acc[4][8] = {};

    for (int kk = 0; kk < 2; ++kk) {
        for (int f = tid; f < 128 * 16; f += 256) {
            int r = f >> 4, e = f & 15;
            Bs[r * 17 + e] = Bf4[(size_t)(n0 + r) * 32 + kk * 16 + e];
        }
        for (int f = tid; f < 64 * 16; f += 256) {
            int r = f >> 4, e = f & 15;
            float4 v = make_float4(0.f, 0.f, 0.f, 0.f);
            if (m0 + r < M) v = Af4[(size_t)(m0 + r) * 32 + kk * 16 + e];
            As[r * 17 + e] = v;
        }
        __syncthreads();
        #pragma unroll
        for (int e = 0; e < 16; ++e) {
            float4 a[4], b[8];
            #pragma unroll
            for (int i = 0; i < 4; ++i) a[i] = As[(r0 + i) * 17 + e];
            #pragma unroll
            for (int j = 0; j < 8; ++j) b[j] = Bs[(cb + j * 16) * 17 + e];
            #pragma unroll
            for (int i = 0; i < 4; ++i) {
                #pragma unroll
                for (int j = 0; j < 8; ++j) {
                    acc[i][j] += a[i].x * b[j].x;
                    acc[i][j] += a[i].y * b[j].y;
                    acc[i][j] += a[i].z * b[j].z;
                    acc[i][j] += a[i].w * b[j].w;
                }
            }
        }
        __syncthreads();
    }

    #pragma unroll
    for (int i = 0; i < 4; ++i) {
        int row = m0 + r0 + i;
        if (row < M) {
            #pragma unroll
            for (int j = 0; j < 8; ++j) {
                int col = n0 + cb + j * 16;
                float v = acc[i][j];
                if (BIAS) v += bias[col];
                C[(size_t)row * N + col] = v;
            }
        }
    }
}

// ---------------------------------------------------------------------------
// Tree encode: gather 31 projected rows, heap-sum in regs, node-max.
// ---------------------------------------------------------------------------
__global__ __launch_bounds__(256) void tree_encode(const int* __restrict__ tok,
                                                   const float* __restrict__ Wemb,
                                                   const float* __restrict__ Wcb,
                                                   float* __restrict__ enc) {
    __shared__ int st[2][NN];
    const int tid = threadIdx.x;
    const int p = tid >> 7;
    const int c = tid & 127;
    const int bl = blockIdx.x * 2;
    if (tid < 2 * NN) {
        int pp = tid / NN, jj = tid - pp * NN;
        st[pp][jj] = tok[(size_t)(bl + pp) * NN + jj];
    }
    __syncthreads();

    float v[NN];
    #pragma unroll
    for (int j = 0; j < NN; ++j)
        v[j] = Wemb[(size_t)st[p][j] * 128 + c];
    #pragma unroll
    for (int i = 14; i >= 0; --i)
        v[i] += v[2 * i + 1] + v[2 * i + 2];

    const float wb = Wcb[c];
    float m = v[0] + 31.f * wb;
    #pragma unroll
    for (int i = 1; i <= 2; ++i)  m = fmaxf(m, v[i] + 15.f * wb);
    #pragma unroll
    for (int i = 3; i <= 6; ++i)  m = fmaxf(m, v[i] + 7.f * wb);
    #pragma unroll
    for (int i = 7; i <= 14; ++i) m = fmaxf(m, v[i] + 3.f * wb);
    #pragma unroll
    for (int i = 15; i <= 30; ++i) m = fmaxf(m, v[i] + wb);

    enc[(size_t)(bl + p) * 128 + c] = m;
}

// ---------------------------------------------------------------------------
// GRU scan v6 = v5 + FORCED register-resident weights.
// v5 evidence: VGPR_Count=68 < 96 weight floats -> compiler rematerialized
// the weight global_loads inside the step loop; 128blk*128step*512thr*384B =
// 3.2 GB of L2 re-reads over 102us ~= 31 TB/s = the L2 ceiling. LLVM targets
// high occupancy and remats invariant loads regardless of __launch_bounds__.
// Fix: (a) amdgpu_waves_per_eu(2,2) pins the allocator budget at 256 VGPR
// (2 waves/EU is exactly what one 512-thr block/CU provides anyway);
// (b) every weight component passes through an opaque asm identity after the
// load -> rematerialization is impossible (value no longer provably equals
// the load), and with a 256-reg budget there is no reason to spill.
// Layout (proven correct in v5): 512 thr = 128 channels x 4 k-quarters, one
// chain/block, 128 blocks. Thread (c,p): Whh rows {c,128+c,256+c}, quarter p
// = 24 float4. Rotated k-chunk order -> conflict-free broadcast LDS reads.
// ---------------------------------------------------------------------------
__device__ __forceinline__ float sigm(float x) { return 1.f / (1.f + __expf(-x)); }
__device__ __forceinline__ float tanh_f(float x) { return 1.f - 2.f / (1.f + __expf(2.f * x)); }

#define PIN_F(x) asm volatile("" : "+v"(x))

__device__ __forceinline__ float dpp_xor1(float x) {
    return __builtin_bit_cast(float,
        __builtin_amdgcn_mov_dpp(__builtin_bit_cast(int, x), 0xB1, 0xF, 0xF, true));
}
__device__ __forceinline__ float dpp_xor2(float x) {
    return __builtin_bit_cast(float,
        __builtin_amdgcn_mov_dpp(__builtin_bit_cast(int, x), 0x4E, 0xF, 0xF, true));
}
__device__ __forceinline__ float quad_sum(float x) {
    x += dpp_xor1(x);
    x += dpp_xor2(x);
    return x;   // all 4 lanes of the quad hold the full sum
}

__global__
__attribute__((amdgpu_flat_work_group_size(512, 512)))
__attribute__((amdgpu_waves_per_eu(2, 2)))
void gru_scan(const float* __restrict__ gi_f,
              const float* __restrict__ gi_b,
              const float* __restrict__ Whh_f,
              const float* __restrict__ Whh_b,
              const float* __restrict__ bhh_f,
              const float* __restrict__ bhh_b,
              float* __restrict__ pooled) {
    const int tid = threadIdx.x;
    const int c   = tid >> 2;     // channel 0..127
    const int p   = tid & 3;      // k-quarter 0..3
    const int dir = blockIdx.x & 1;
    const int b   = blockIdx.x >> 1;   // 0..63 with 128 blocks
    const float* gi  = dir ? gi_b  : gi_f;
    const float* Whh = dir ? Whh_b : Whh_f;
    const float* bhh = dir ? bhh_b : bhh_f;

    __shared__ __align__(16) float hbuf[2][128];

    // weights, k-chunk order rotated by 2p (bank-conflict-free LDS reads):
    // w[r][i] corresponds to k-chunk p*8 + ((i+2p)&7)
    float4 w[3][8];
    const float4* wf4 = (const float4*)Whh;
    #pragma unroll
    for (int r = 0; r < 3; ++r)
        #pragma unroll
        for (int i = 0; i < 8; ++i)
            w[r][i] = wf4[(size_t)(r * 128 + c) * 32 + p * 8 + ((i + 2 * p) & 7)];
    // opaque pin: kills load rematerialization (the L2-BW killer in v2/v5)
    #pragma unroll
    for (int r = 0; r < 3; ++r)
        #pragma unroll
        for (int i = 0; i < 8; ++i) {
            PIN_F(w[r][i].x); PIN_F(w[r][i].y);
            PIN_F(w[r][i].z); PIN_F(w[r][i].w);
        }

    float bh_r = 0.f, bh_z = 0.f, bh_n = 0.f;
    if (p == 0) { bh_r = bhh[c]; bh_z = bhh[128 + c]; bh_n = bhh[256 + c]; }

    float hold = 0.f, m = -INFINITY;
    if (tid < 128) hbuf[0][tid] = 0.f;

    // prefetch gi for steps 0 and 1 (p==0 lanes only)
    float g0r = 0.f, g0z = 0.f, g0n = 0.f, g1r = 0.f, g1z = 0.f, g1n = 0.f;
    if (p == 0) {
        const float* row0 = gi + ((size_t)b * LL + (dir ? LL - 1 : 0)) * 384;
        g0r = row0[c]; g0z = row0[128 + c]; g0n = row0[256 + c];
        const float* row1 = gi + ((size_t)b * LL + (dir ? LL - 2 : 1)) * 384;
        g1r = row1[c]; g1z = row1[128 + c]; g1n = row1[256 + c];
    }
    __syncthreads();   // publish hbuf[0]

    for (int s = 0; s < LL; ++s) {
        const int cur = s & 1;
        // prefetch gi for step s+2
        float g2r = 0.f, g2z = 0.f, g2n = 0.f;
        if (p == 0 && s + 2 < LL) {
            const int t2 = dir ? (LL - 3 - s) : (s + 2);
            const float* row = gi + ((size_t)b * LL + t2) * 384;
            g2r = row[c]; g2z = row[128 + c]; g2n = row[256 + c];
        }

        // partial matvec over this thread's k-quarter, rotated chunk order
        const float4* hq = (const float4*)hbuf[cur];
        float a0 = 0.f, a1 = 0.f, a2 = 0.f;
        #pragma unroll
        for (int i = 0; i < 8; ++i) {
            const float4 hv = hq[p * 8 + ((i + 2 * p) & 7)];
            a0 += w[0][i].x * hv.x + w[0][i].y * hv.y + w[0][i].z * hv.z + w[0][i].w * hv.w;
            a1 += w[1][i].x * hv.x + w[1][i].y * hv.y + w[1][i].z * hv.z + w[1][i].w * hv.w;
            a2 += w[2][i].x * hv.x + w[2][i].y * hv.y + w[2][i].z * hv.z + w[2][i].w * hv.w;
        }
        a0 = quad_sum(a0); a1 = quad_sum(a1); a2 = quad_sum(a2);

        if (p == 0) {
            const float r = sigm(g0r + a0 + bh_r);
            const float z = sigm(g0z + a1 + bh_z);
            const float n = tanh_f(g0n + r * (a2 + bh_n));
            const float hn = (1.f - z) * n + z * hold;
            hold = hn;
            m = fmaxf(m, hn);
            hbuf[cur ^ 1][c] = hn;
        }
        g0r = g1r; g0z = g1z; g0n = g1n;
        g1r = g2r; g1z = g2z; g1n = g2n;
        __syncthreads();   // publish hbuf[cur^1] for next step
    }
    if (p == 0) pooled[((size_t)b * 2 + dir) * 128 + c] = m;
}

// ---------------------------------------------------------------------------
// Output head: out[b,o] = pooled[b,:]·Wout[o,:] + bout[o]   (64 x 104 x 256)
// ---------------------------------------------------------------------------
__global__ __launch_bounds__(128) void out_head(const float* __restrict__ pooled,
                                                const float* __restrict__ Wout,
                                                const float* __restrict__ bout,
                                                float* __restrict__ out) {
    __shared__ __align__(16) float pbuf[256];
    const int b = blockIdx.x, o = threadIdx.x;
    if (o < 64) ((float4*)pbuf)[o] = ((const float4*)(pooled + (size_t)b * 256))[o];
    __syncthreads();
    if (o < NLBL) {
        float acc = bout[o];
        const float4* wf4 = (const float4*)(Wout + (size_t)o * 256);
        const float4* pf4 = (const float4*)pbuf;
        #pragma unroll 8
        for (int q = 0; q < 64; ++q) {
            float4 wv = wf4[q], pv = pf4[q];
            acc += wv.x * pv.x + wv.y * pv.y + wv.z * pv.z + wv.w * pv.w;
        }
        out[(size_t)b * NLBL + o] = acc;
    }
}

// ---------------------------------------------------------------------------
extern "C" void kernel_launch(void* const* d_in, const int* in_sizes, int n_in,
                              void* d_out, int out_size, void* d_ws, size_t ws_size,
                              hipStream_t stream) {
    const int*   tokens = (const int*)  d_in[0];
    const float* emb    = (const float*)d_in[1];
    const float* Wc_w   = (const float*)d_in[2];
    const float* Wc_b   = (const float*)d_in[3];
    const float* Wih_f  = (const float*)d_in[4];
    const float* Whh_f  = (const float*)d_in[5];
    const float* bih_f  = (const float*)d_in[6];
    const float* bhh_f  = (const float*)d_in[7];
    const float* Wih_b  = (const float*)d_in[8];
    const float* Whh_b  = (const float*)d_in[9];
    const float* bih_b  = (const float*)d_in[10];
    const float* bhh_b  = (const float*)d_in[11];
    const float* Wout   = (const float*)d_in[12];
    const float* bout   = (const float*)d_in[13];
    float* out = (float*)d_out;
    float* ws  = (float*)d_ws;

    float* Wemb = ws;                                   // 50000*128
    float* enc  = Wemb + (size_t)VV * 128;              // 8192*128
    float* gi_f = enc  + (size_t)BB * LL * 128;         // 8192*384
    float* gi_b = gi_f + (size_t)BB * LL * 384;         // 8192*384
    float* pool = gi_b + (size_t)BB * LL * 384;         // 64*256

    // 1. projected embedding table: Wemb = emb @ Wc_w^T  (1.64 GFLOP)
    gemm128<false><<<dim3(782, 1, 1), 256, 0, stream>>>(
        emb, Wc_w, Wc_w, nullptr, nullptr, Wemb, Wemb, VV, 128);
    // 2. gather + tree-sum + node-max -> encodes (8192 x 128)
    tree_encode<<<dim3(4096), 256, 0, stream>>>(tokens, Wemb, Wc_b, enc);
    // 3. input gates, both directions in ONE dispatch (z selects dir)
    gemm128<true><<<dim3(128, 3, 2), 256, 0, stream>>>(
        enc, Wih_f, Wih_b, bih_f, bih_b, gi_f, gi_b, BB * LL, 384);
    // 4. sequential GRU scans: 128 chains (64 b x 2 dir) -> 128 BLOCKS
    gru_scan<<<dim3(128), 512, 0, stream>>>(gi_f, gi_b, Whh_f, Whh_b, bhh_f, bhh_b, pool);
    // 5. output head
    out_head<<<dim3(64), 128, 0, stream>>>(pool, Wout, bout, out);
}